// Round 1
// baseline (1220.431 us; speedup 1.0000x reference)
//
#include <hip/hip_runtime.h>
#include <hip/hip_bf16.h>

#define N_NODES 100000
#define N_EDGES 1600000
#define E_TOT   (N_EDGES + N_NODES)   // + self loops
#define NEG_SLOPE 0.2f

// ---------------- CSR build ----------------

__global__ void degree_kernel(const int* __restrict__ dst, int* __restrict__ deg, int n) {
    int i = blockIdx.x * blockDim.x + threadIdx.x;
    if (i < n) atomicAdd(&deg[dst[i]], 1);
}

#define SCAN_BLOCK 256
#define SCAN_ITEMS 4
#define SCAN_NB ((N_NODES + SCAN_BLOCK * SCAN_ITEMS - 1) / (SCAN_BLOCK * SCAN_ITEMS))  // 98

__global__ void scan_partial(const int* __restrict__ deg, int* __restrict__ bsum, int n) {
    __shared__ int lds[SCAN_BLOCK];
    int base = blockIdx.x * SCAN_BLOCK * SCAN_ITEMS + threadIdx.x * SCAN_ITEMS;
    int s = 0;
    #pragma unroll
    for (int i = 0; i < SCAN_ITEMS; ++i) {
        int idx = base + i;
        if (idx < n) s += deg[idx] + 1;   // +1 = self loop
    }
    lds[threadIdx.x] = s;
    __syncthreads();
    for (int off = SCAN_BLOCK / 2; off; off >>= 1) {
        if (threadIdx.x < off) lds[threadIdx.x] += lds[threadIdx.x + off];
        __syncthreads();
    }
    if (threadIdx.x == 0) bsum[blockIdx.x] = lds[0];
}

__global__ void scan_bsum(int* bsum, int nb) {
    if (threadIdx.x == 0 && blockIdx.x == 0) {
        int acc = 0;
        for (int b = 0; b < nb; ++b) { int v = bsum[b]; bsum[b] = acc; acc += v; }
    }
}

__global__ void scan_final(const int* __restrict__ deg, const int* __restrict__ bsum,
                           int* __restrict__ rowptr, int* __restrict__ cursor, int n, int etot) {
    __shared__ int lds[SCAN_BLOCK];
    int tid = threadIdx.x;
    int base = blockIdx.x * SCAN_BLOCK * SCAN_ITEMS + tid * SCAN_ITEMS;
    int vals[SCAN_ITEMS];
    int s = 0;
    #pragma unroll
    for (int i = 0; i < SCAN_ITEMS; ++i) {
        int idx = base + i;
        vals[i] = (idx < n) ? deg[idx] + 1 : 0;
        s += vals[i];
    }
    lds[tid] = s;
    __syncthreads();
    // Hillis-Steele inclusive scan of thread sums
    for (int off = 1; off < SCAN_BLOCK; off <<= 1) {
        int v = 0;
        if (tid >= off) v = lds[tid - off];
        __syncthreads();
        if (tid >= off) lds[tid] += v;
        __syncthreads();
    }
    int excl = bsum[blockIdx.x] + lds[tid] - s;
    #pragma unroll
    for (int i = 0; i < SCAN_ITEMS; ++i) {
        int idx = base + i;
        if (idx < n) { rowptr[idx] = excl; cursor[idx] = excl; }
        excl += vals[i];
    }
    if (blockIdx.x == 0 && tid == 0) rowptr[n] = etot;
}

__global__ void scatter_kernel(const int* __restrict__ ei, int* __restrict__ cursor,
                               int* __restrict__ csr, int E, int etot) {
    int e = blockIdx.x * blockDim.x + threadIdx.x;
    if (e >= etot) return;
    int s, d;
    if (e < E) { s = ei[e]; d = ei[E + e]; }
    else       { s = d = e - E; }
    int pos = atomicAdd(&cursor[d], 1);
    csr[pos] = s;
}

// ---------------- GEMM: C[n,j] = sum_k A[n,k] * W[k,j] ----------------
// block: ROWS rows x (J/JT) colgroups = 256 threads; W fully in LDS.

template<int K, int J, int JT, int ROWS>
__global__ __launch_bounds__(256) void gemm_kernel(const float* __restrict__ A,
                                                   const float* __restrict__ W,
                                                   float* __restrict__ C, int n) {
    constexpr int TPR = J / JT;    // 8
    __shared__ float w_lds[K * J];
    constexpr int TOT = K * J;
    for (int i = threadIdx.x * 4; i < TOT; i += 256 * 4) {
        *(float4*)&w_lds[i] = *(const float4*)&W[i];
    }
    __syncthreads();
    int r  = threadIdx.x / TPR;
    int cg = threadIdx.x % TPR;
    int row = blockIdx.x * ROWS + r;
    if (row >= n) return;
    const float* a = A + (size_t)row * K;
    float acc[JT];
    #pragma unroll
    for (int c = 0; c < JT; ++c) acc[c] = 0.f;
    int j0 = cg * JT;
    for (int k = 0; k < K; k += 4) {
        float4 xv = *(const float4*)&a[k];
        const float* wr0 = &w_lds[(k + 0) * J + j0];
        const float* wr1 = &w_lds[(k + 1) * J + j0];
        const float* wr2 = &w_lds[(k + 2) * J + j0];
        const float* wr3 = &w_lds[(k + 3) * J + j0];
        #pragma unroll
        for (int c = 0; c < JT; ++c) acc[c] += xv.x * wr0[c];
        #pragma unroll
        for (int c = 0; c < JT; ++c) acc[c] += xv.y * wr1[c];
        #pragma unroll
        for (int c = 0; c < JT; ++c) acc[c] += xv.z * wr2[c];
        #pragma unroll
        for (int c = 0; c < JT; ++c) acc[c] += xv.w * wr3[c];
    }
    float* cptr = C + (size_t)row * J + j0;
    #pragma unroll
    for (int c = 0; c < JT; ++c) cptr[c] = acc[c];
}

// ---------------- attention scores: s[n,h] = <h[n,h,:], att[h,:]> ----------------

template<int C, int J>
__global__ void score_kernel(const float* __restrict__ h, const float* __restrict__ att_src,
                             const float* __restrict__ att_dst,
                             float* __restrict__ s_src, float* __restrict__ s_dst, int n) {
    int idx = blockIdx.x * blockDim.x + threadIdx.x;   // node*4 + head
    if (idx >= n * 4) return;
    int node = idx >> 2, hd = idx & 3;
    const float* hp = h + (size_t)node * J + hd * C;
    const float* as = att_src + hd * C;
    const float* ad = att_dst + hd * C;
    float ss = 0.f, sd = 0.f;
    #pragma unroll
    for (int c = 0; c < C; ++c) { float v = hp[c]; ss += v * as[c]; sd += v * ad[c]; }
    s_src[idx] = ss;
    s_dst[idx] = sd;
}

// ---------------- layer-1 aggregation (+bias +ELU) ----------------
// one wave per dst node; lane owns 2 of 128 cols.

__global__ __launch_bounds__(64) void agg1_kernel(
        const float* __restrict__ h1, const float* __restrict__ s_src,
        const float* __restrict__ s_dst, const int* __restrict__ rowptr,
        const int* __restrict__ csr, const float* __restrict__ b1,
        float* __restrict__ out1) {
    int d = blockIdx.x;
    int lane = threadIdx.x;
    int c0 = lane * 2;
    int hd = c0 >> 5;
    float sdst = s_dst[d * 4 + hd];
    float accx = 0.f, accy = 0.f, z = 0.f;
    int beg = rowptr[d], end = rowptr[d + 1];
    for (int j = beg; j < end; ++j) {
        int s = csr[j];
        float e = s_src[s * 4 + hd] + sdst;
        e = e > 0.f ? e : NEG_SLOPE * e;
        float p = __expf(e);
        float2 hv = *(const float2*)&h1[(size_t)s * 128 + c0];
        accx += p * hv.x;
        accy += p * hv.y;
        z += p;
    }
    float invz = 1.0f / z;
    float vx = accx * invz + b1[c0];
    float vy = accy * invz + b1[c0 + 1];
    vx = vx > 0.f ? vx : __expf(vx) - 1.0f;   // ELU
    vy = vy > 0.f ? vy : __expf(vy) - 1.0f;
    *(float2*)&out1[(size_t)d * 128 + c0] = make_float2(vx, vy);
}

// ---------------- layer-2 aggregation + head mean + b2 + log_softmax ----------------
// 4 waves per dst node, wave = head; lanes 0..39 own the 40 cols of that head.

__global__ __launch_bounds__(256) void agg2_kernel(
        const float* __restrict__ h2, const float* __restrict__ s_src,
        const float* __restrict__ s_dst, const int* __restrict__ rowptr,
        const int* __restrict__ csr, const float* __restrict__ b2,
        float* __restrict__ out) {
    int d = blockIdx.x;
    int w = threadIdx.x >> 6;      // head
    int lane = threadIdx.x & 63;
    __shared__ float red[4][40];
    float sdst = s_dst[d * 4 + w];
    bool active = lane < 40;
    float acc = 0.f, z = 0.f;
    int beg = rowptr[d], end = rowptr[d + 1];
    for (int j = beg; j < end; ++j) {
        int s = csr[j];
        float e = s_src[s * 4 + w] + sdst;
        e = e > 0.f ? e : NEG_SLOPE * e;
        float p = __expf(e);
        z += p;
        if (active) acc += p * h2[(size_t)s * 160 + w * 40 + lane];
    }
    if (active) red[w][lane] = acc / z;
    __syncthreads();
    if (w == 0) {
        float v = -1e30f;
        if (active)
            v = (red[0][lane] + red[1][lane] + red[2][lane] + red[3][lane]) * 0.25f + b2[lane];
        float m = v;
        #pragma unroll
        for (int off = 32; off; off >>= 1) m = fmaxf(m, __shfl_xor(m, off));
        float ex = active ? __expf(v - m) : 0.f;
        float sum = ex;
        #pragma unroll
        for (int off = 32; off; off >>= 1) sum += __shfl_xor(sum, off);
        if (active) out[(size_t)d * 40 + lane] = v - m - __logf(sum);
    }
}

// ---------------- launch ----------------

extern "C" void kernel_launch(void* const* d_in, const int* in_sizes, int n_in,
                              void* d_out, int out_size, void* d_ws, size_t ws_size,
                              hipStream_t stream) {
    const float* x   = (const float*)d_in[0];
    const int*   ei  = (const int*)d_in[1];
    const float* W1  = (const float*)d_in[2];
    const float* as1 = (const float*)d_in[3];
    const float* ad1 = (const float*)d_in[4];
    const float* b1  = (const float*)d_in[5];
    const float* W2  = (const float*)d_in[6];
    const float* as2 = (const float*)d_in[7];
    const float* ad2 = (const float*)d_in[8];
    const float* b2  = (const float*)d_in[9];
    float* out = (float*)d_out;

    char* ws = (char*)d_ws;
    size_t off = 0;
    auto alloc = [&](size_t bytes) {
        void* p = ws + off;
        off += (bytes + 255) & ~(size_t)255;
        return p;
    };
    float* h1      = (float*)alloc((size_t)N_NODES * 128 * 4);
    float* out1    = (float*)alloc((size_t)N_NODES * 128 * 4);
    float* h2      = (float*)alloc((size_t)N_NODES * 160 * 4);
    float* s_src1  = (float*)alloc((size_t)N_NODES * 4 * 4);
    float* s_dst1  = (float*)alloc((size_t)N_NODES * 4 * 4);
    float* s_src2  = (float*)alloc((size_t)N_NODES * 4 * 4);
    float* s_dst2  = (float*)alloc((size_t)N_NODES * 4 * 4);
    int*   deg     = (int*)alloc((size_t)N_NODES * 4);
    int*   rowptr  = (int*)alloc((size_t)(N_NODES + 1) * 4);
    int*   cursor  = (int*)alloc((size_t)N_NODES * 4);
    int*   csr     = (int*)alloc((size_t)E_TOT * 4);
    int*   bsum    = (int*)alloc((size_t)SCAN_NB * 4);

    // CSR build
    hipMemsetAsync(deg, 0, (size_t)N_NODES * 4, stream);
    degree_kernel<<<(N_EDGES + 255) / 256, 256, 0, stream>>>(ei + N_EDGES, deg, N_EDGES);
    scan_partial<<<SCAN_NB, SCAN_BLOCK, 0, stream>>>(deg, bsum, N_NODES);
    scan_bsum<<<1, 64, 0, stream>>>(bsum, SCAN_NB);
    scan_final<<<SCAN_NB, SCAN_BLOCK, 0, stream>>>(deg, bsum, rowptr, cursor, N_NODES, E_TOT);
    scatter_kernel<<<(E_TOT + 255) / 256, 256, 0, stream>>>(ei, cursor, csr, N_EDGES, E_TOT);

    // layer 1
    gemm_kernel<128, 128, 16, 32><<<(N_NODES + 31) / 32, 256, 0, stream>>>(x, W1, h1, N_NODES);
    score_kernel<32, 128><<<(N_NODES * 4 + 255) / 256, 256, 0, stream>>>(h1, as1, ad1, s_src1, s_dst1, N_NODES);
    agg1_kernel<<<N_NODES, 64, 0, stream>>>(h1, s_src1, s_dst1, rowptr, csr, b1, out1);

    // layer 2
    gemm_kernel<128, 160, 20, 32><<<(N_NODES + 31) / 32, 256, 0, stream>>>(out1, W2, h2, N_NODES);
    score_kernel<40, 160><<<(N_NODES * 4 + 255) / 256, 256, 0, stream>>>(h2, as2, ad2, s_src2, s_dst2, N_NODES);
    agg2_kernel<<<N_NODES, 256, 0, stream>>>(h2, s_src2, s_dst2, rowptr, csr, b2, out);
}

// Round 2
// 775.464 us; speedup vs baseline: 1.5738x; 1.5738x over previous
//
#include <hip/hip_runtime.h>
#include <hip/hip_bf16.h>

#define N_NODES 100000
#define N_EDGES 1600000
#define E_TOT   (N_EDGES + N_NODES)   // + self loops
#define NEG_SLOPE 0.2f

// ---------------- CSR build ----------------

__global__ void degree_kernel(const int* __restrict__ dst, int* __restrict__ deg, int n) {
    int i = blockIdx.x * blockDim.x + threadIdx.x;
    if (i < n) atomicAdd(&deg[dst[i]], 1);
}

#define SCAN_BLOCK 256
#define SCAN_ITEMS 4
#define SCAN_NB ((N_NODES + SCAN_BLOCK * SCAN_ITEMS - 1) / (SCAN_BLOCK * SCAN_ITEMS))  // 98

__global__ void scan_partial(const int* __restrict__ deg, int* __restrict__ bsum, int n) {
    __shared__ int lds[SCAN_BLOCK];
    int base = blockIdx.x * SCAN_BLOCK * SCAN_ITEMS + threadIdx.x * SCAN_ITEMS;
    int s = 0;
    #pragma unroll
    for (int i = 0; i < SCAN_ITEMS; ++i) {
        int idx = base + i;
        if (idx < n) s += deg[idx] + 1;   // +1 = self loop
    }
    lds[threadIdx.x] = s;
    __syncthreads();
    for (int off = SCAN_BLOCK / 2; off; off >>= 1) {
        if (threadIdx.x < off) lds[threadIdx.x] += lds[threadIdx.x + off];
        __syncthreads();
    }
    if (threadIdx.x == 0) bsum[blockIdx.x] = lds[0];
}

__global__ void scan_bsum(int* bsum, int nb) {
    if (threadIdx.x == 0 && blockIdx.x == 0) {
        int acc = 0;
        for (int b = 0; b < nb; ++b) { int v = bsum[b]; bsum[b] = acc; acc += v; }
    }
}

__global__ void scan_final(const int* __restrict__ deg, const int* __restrict__ bsum,
                           int* __restrict__ rowptr, int* __restrict__ cursor, int n, int etot) {
    __shared__ int lds[SCAN_BLOCK];
    int tid = threadIdx.x;
    int base = blockIdx.x * SCAN_BLOCK * SCAN_ITEMS + tid * SCAN_ITEMS;
    int vals[SCAN_ITEMS];
    int s = 0;
    #pragma unroll
    for (int i = 0; i < SCAN_ITEMS; ++i) {
        int idx = base + i;
        vals[i] = (idx < n) ? deg[idx] + 1 : 0;
        s += vals[i];
    }
    lds[tid] = s;
    __syncthreads();
    for (int off = 1; off < SCAN_BLOCK; off <<= 1) {
        int v = 0;
        if (tid >= off) v = lds[tid - off];
        __syncthreads();
        if (tid >= off) lds[tid] += v;
        __syncthreads();
    }
    int excl = bsum[blockIdx.x] + lds[tid] - s;
    #pragma unroll
    for (int i = 0; i < SCAN_ITEMS; ++i) {
        int idx = base + i;
        if (idx < n) { rowptr[idx] = excl; cursor[idx] = excl; }
        excl += vals[i];
    }
    if (blockIdx.x == 0 && tid == 0) rowptr[n] = etot;
}

__global__ void scatter_kernel(const int* __restrict__ ei, int* __restrict__ cursor,
                               int* __restrict__ csr, int* __restrict__ csrd,
                               int E, int etot) {
    int e = blockIdx.x * blockDim.x + threadIdx.x;
    if (e >= etot) return;
    int s, d;
    if (e < E) { s = ei[e]; d = ei[E + e]; }
    else       { s = d = e - E; }
    int pos = atomicAdd(&cursor[d], 1);
    csr[pos] = s;
    csrd[pos] = d;
}

// ---------------- GEMM: C[n,j] = sum_k A[n,k] * W[k,j] ----------------

template<int K, int J, int JT, int ROWS>
__global__ __launch_bounds__(256) void gemm_kernel(const float* __restrict__ A,
                                                   const float* __restrict__ W,
                                                   float* __restrict__ C, int n) {
    constexpr int TPR = J / JT;
    __shared__ float w_lds[K * J];
    constexpr int TOT = K * J;
    for (int i = threadIdx.x * 4; i < TOT; i += 256 * 4) {
        *(float4*)&w_lds[i] = *(const float4*)&W[i];
    }
    __syncthreads();
    int r  = threadIdx.x / TPR;
    int cg = threadIdx.x % TPR;
    int row = blockIdx.x * ROWS + r;
    if (row >= n) return;
    const float* a = A + (size_t)row * K;
    float acc[JT];
    #pragma unroll
    for (int c = 0; c < JT; ++c) acc[c] = 0.f;
    int j0 = cg * JT;
    for (int k = 0; k < K; k += 4) {
        float4 xv = *(const float4*)&a[k];
        const float* wr0 = &w_lds[(k + 0) * J + j0];
        const float* wr1 = &w_lds[(k + 1) * J + j0];
        const float* wr2 = &w_lds[(k + 2) * J + j0];
        const float* wr3 = &w_lds[(k + 3) * J + j0];
        #pragma unroll
        for (int c = 0; c < JT; ++c) acc[c] += xv.x * wr0[c];
        #pragma unroll
        for (int c = 0; c < JT; ++c) acc[c] += xv.y * wr1[c];
        #pragma unroll
        for (int c = 0; c < JT; ++c) acc[c] += xv.z * wr2[c];
        #pragma unroll
        for (int c = 0; c < JT; ++c) acc[c] += xv.w * wr3[c];
    }
    float* cptr = C + (size_t)row * J + j0;
    #pragma unroll
    for (int c = 0; c < JT; ++c) cptr[c] = acc[c];
}

// ---------------- attention scores: s[n,h] = <h[n,h,:], att[h,:]> ----------------

template<int C, int J>
__global__ void score_kernel(const float* __restrict__ h, const float* __restrict__ att_src,
                             const float* __restrict__ att_dst,
                             float* __restrict__ s_src, float* __restrict__ s_dst, int n) {
    int idx = blockIdx.x * blockDim.x + threadIdx.x;   // node*4 + head
    if (idx >= n * 4) return;
    int node = idx >> 2, hd = idx & 3;
    const float* hp = h + (size_t)node * J + hd * C;
    const float* as = att_src + hd * C;
    const float* ad = att_dst + hd * C;
    float ss = 0.f, sd = 0.f;
    #pragma unroll
    for (int c = 0; c < C; ++c) { float v = hp[c]; ss += v * as[c]; sd += v * ad[c]; }
    s_src[idx] = ss;
    s_dst[idx] = sd;
}

// ---------------- per-edge unnormalized softmax weights (CSR order) ----------------

__global__ void edge_p_kernel(const int* __restrict__ csr, const int* __restrict__ csrd,
                              const float* __restrict__ s_src, const float* __restrict__ s_dst,
                              float* __restrict__ p4, int etot) {
    int j = blockIdx.x * blockDim.x + threadIdx.x;
    if (j >= etot) return;
    int s = csr[j], d = csrd[j];
    float4 a = *(const float4*)&s_src[(size_t)s * 4];
    float4 b = *(const float4*)&s_dst[(size_t)d * 4];
    float4 r;
    float e;
    e = a.x + b.x; e = e > 0.f ? e : NEG_SLOPE * e; r.x = __expf(e);
    e = a.y + b.y; e = e > 0.f ? e : NEG_SLOPE * e; r.y = __expf(e);
    e = a.z + b.z; e = e > 0.f ? e : NEG_SLOPE * e; r.z = __expf(e);
    e = a.w + b.w; e = e > 0.f ? e : NEG_SLOPE * e; r.w = __expf(e);
    *(float4*)&p4[(size_t)j * 4] = r;
}

// ---------------- layer-1 aggregation (+bias +ELU) ----------------
// 4 dst per 256-thread block, one wave per dst; lane owns 2 of 128 cols.
// Edge loop unrolled x4 -> 4 independent row gathers in flight.

__global__ __launch_bounds__(256) void agg1_kernel(
        const float* __restrict__ h1, const float* __restrict__ p4,
        const int* __restrict__ rowptr, const int* __restrict__ csr,
        const float* __restrict__ b1, float* __restrict__ out1) {
    int d = blockIdx.x * 4 + (threadIdx.x >> 6);
    if (d >= N_NODES) return;
    int lane = threadIdx.x & 63;
    int c0 = lane * 2;
    int hd = c0 >> 5;
    float accx = 0.f, accy = 0.f, z = 0.f;
    int beg = rowptr[d], end = rowptr[d + 1];
    int j = beg;
    for (; j + 3 < end; j += 4) {
        int s0 = csr[j], s1 = csr[j + 1], s2 = csr[j + 2], s3 = csr[j + 3];
        float q0 = p4[(size_t)(j + 0) * 4 + hd];
        float q1 = p4[(size_t)(j + 1) * 4 + hd];
        float q2 = p4[(size_t)(j + 2) * 4 + hd];
        float q3 = p4[(size_t)(j + 3) * 4 + hd];
        float2 v0 = *(const float2*)&h1[(size_t)s0 * 128 + c0];
        float2 v1 = *(const float2*)&h1[(size_t)s1 * 128 + c0];
        float2 v2 = *(const float2*)&h1[(size_t)s2 * 128 + c0];
        float2 v3 = *(const float2*)&h1[(size_t)s3 * 128 + c0];
        accx += q0 * v0.x; accy += q0 * v0.y;
        accx += q1 * v1.x; accy += q1 * v1.y;
        accx += q2 * v2.x; accy += q2 * v2.y;
        accx += q3 * v3.x; accy += q3 * v3.y;
        z += q0 + q1 + q2 + q3;
    }
    for (; j < end; ++j) {
        int s = csr[j];
        float q = p4[(size_t)j * 4 + hd];
        float2 v = *(const float2*)&h1[(size_t)s * 128 + c0];
        accx += q * v.x; accy += q * v.y;
        z += q;
    }
    float invz = 1.0f / z;
    float vx = accx * invz + b1[c0];
    float vy = accy * invz + b1[c0 + 1];
    vx = vx > 0.f ? vx : __expf(vx) - 1.0f;   // ELU
    vy = vy > 0.f ? vy : __expf(vy) - 1.0f;
    *(float2*)&out1[(size_t)d * 128 + c0] = make_float2(vx, vy);
}

// ---------------- layer-2 aggregation + head mean + b2 + log_softmax ----------------
// 4 waves per dst node, wave = head; lanes 0..39 own the 40 cols of that head.

__global__ __launch_bounds__(256) void agg2_kernel(
        const float* __restrict__ h2, const float* __restrict__ p4,
        const int* __restrict__ rowptr, const int* __restrict__ csr,
        const float* __restrict__ b2, float* __restrict__ out) {
    int d = blockIdx.x;
    int w = threadIdx.x >> 6;      // head
    int lane = threadIdx.x & 63;
    __shared__ float red[4][40];
    bool active = lane < 40;
    int col = w * 40 + lane;
    float acc = 0.f, z = 0.f;
    int beg = rowptr[d], end = rowptr[d + 1];
    int j = beg;
    for (; j + 3 < end; j += 4) {
        int s0 = csr[j], s1 = csr[j + 1], s2 = csr[j + 2], s3 = csr[j + 3];
        float q0 = p4[(size_t)(j + 0) * 4 + w];
        float q1 = p4[(size_t)(j + 1) * 4 + w];
        float q2 = p4[(size_t)(j + 2) * 4 + w];
        float q3 = p4[(size_t)(j + 3) * 4 + w];
        float v0 = 0.f, v1 = 0.f, v2 = 0.f, v3 = 0.f;
        if (active) {
            v0 = h2[(size_t)s0 * 160 + col];
            v1 = h2[(size_t)s1 * 160 + col];
            v2 = h2[(size_t)s2 * 160 + col];
            v3 = h2[(size_t)s3 * 160 + col];
        }
        acc += q0 * v0 + q1 * v1 + q2 * v2 + q3 * v3;
        z += q0 + q1 + q2 + q3;
    }
    for (; j < end; ++j) {
        int s = csr[j];
        float q = p4[(size_t)j * 4 + w];
        float v = active ? h2[(size_t)s * 160 + col] : 0.f;
        acc += q * v;
        z += q;
    }
    if (active) red[w][lane] = acc / z;
    __syncthreads();
    if (w == 0) {
        float v = -1e30f;
        if (active)
            v = (red[0][lane] + red[1][lane] + red[2][lane] + red[3][lane]) * 0.25f + b2[lane];
        float m = v;
        #pragma unroll
        for (int off = 32; off; off >>= 1) m = fmaxf(m, __shfl_xor(m, off));
        float ex = active ? __expf(v - m) : 0.f;
        float sum = ex;
        #pragma unroll
        for (int off = 32; off; off >>= 1) sum += __shfl_xor(sum, off);
        if (active) out[(size_t)d * 40 + lane] = v - m - __logf(sum);
    }
}

// ---------------- launch ----------------

extern "C" void kernel_launch(void* const* d_in, const int* in_sizes, int n_in,
                              void* d_out, int out_size, void* d_ws, size_t ws_size,
                              hipStream_t stream) {
    const float* x   = (const float*)d_in[0];
    const int*   ei  = (const int*)d_in[1];
    const float* W1  = (const float*)d_in[2];
    const float* as1 = (const float*)d_in[3];
    const float* ad1 = (const float*)d_in[4];
    const float* b1  = (const float*)d_in[5];
    const float* W2  = (const float*)d_in[6];
    const float* as2 = (const float*)d_in[7];
    const float* ad2 = (const float*)d_in[8];
    const float* b2  = (const float*)d_in[9];
    float* out = (float*)d_out;

    char* ws = (char*)d_ws;
    size_t off = 0;
    auto alloc = [&](size_t bytes) {
        void* p = ws + off;
        off += (bytes + 255) & ~(size_t)255;
        return p;
    };
    float* h1      = (float*)alloc((size_t)N_NODES * 128 * 4);
    float* out1    = (float*)alloc((size_t)N_NODES * 128 * 4);
    float* h2      = (float*)alloc((size_t)N_NODES * 160 * 4);
    float* s_src1  = (float*)alloc((size_t)N_NODES * 4 * 4);
    float* s_dst1  = (float*)alloc((size_t)N_NODES * 4 * 4);
    float* s_src2  = (float*)alloc((size_t)N_NODES * 4 * 4);
    float* s_dst2  = (float*)alloc((size_t)N_NODES * 4 * 4);
    float* p4      = (float*)alloc((size_t)E_TOT * 4 * 4);
    int*   deg     = (int*)alloc((size_t)N_NODES * 4);
    int*   rowptr  = (int*)alloc((size_t)(N_NODES + 1) * 4);
    int*   cursor  = (int*)alloc((size_t)N_NODES * 4);
    int*   csr     = (int*)alloc((size_t)E_TOT * 4);
    int*   csrd    = (int*)alloc((size_t)E_TOT * 4);
    int*   bsum    = (int*)alloc((size_t)SCAN_NB * 4);

    // CSR build
    hipMemsetAsync(deg, 0, (size_t)N_NODES * 4, stream);
    degree_kernel<<<(N_EDGES + 255) / 256, 256, 0, stream>>>(ei + N_EDGES, deg, N_EDGES);
    scan_partial<<<SCAN_NB, SCAN_BLOCK, 0, stream>>>(deg, bsum, N_NODES);
    scan_bsum<<<1, 64, 0, stream>>>(bsum, SCAN_NB);
    scan_final<<<SCAN_NB, SCAN_BLOCK, 0, stream>>>(deg, bsum, rowptr, cursor, N_NODES, E_TOT);
    scatter_kernel<<<(E_TOT + 255) / 256, 256, 0, stream>>>(ei, cursor, csr, csrd, N_EDGES, E_TOT);

    // layer 1
    gemm_kernel<128, 128, 16, 32><<<(N_NODES + 31) / 32, 256, 0, stream>>>(x, W1, h1, N_NODES);
    score_kernel<32, 128><<<(N_NODES * 4 + 255) / 256, 256, 0, stream>>>(h1, as1, ad1, s_src1, s_dst1, N_NODES);
    edge_p_kernel<<<(E_TOT + 255) / 256, 256, 0, stream>>>(csr, csrd, s_src1, s_dst1, p4, E_TOT);
    agg1_kernel<<<(N_NODES + 3) / 4, 256, 0, stream>>>(h1, p4, rowptr, csr, b1, out1);

    // layer 2
    gemm_kernel<128, 160, 20, 32><<<(N_NODES + 31) / 32, 256, 0, stream>>>(out1, W2, h2, N_NODES);
    score_kernel<40, 160><<<(N_NODES * 4 + 255) / 256, 256, 0, stream>>>(h2, as2, ad2, s_src2, s_dst2, N_NODES);
    edge_p_kernel<<<(E_TOT + 255) / 256, 256, 0, stream>>>(csr, csrd, s_src2, s_dst2, p4, E_TOT);
    agg2_kernel<<<N_NODES, 256, 0, stream>>>(h2, p4, rowptr, csr, b2, out);
}

// Round 3
// 494.924 us; speedup vs baseline: 2.4659x; 1.5668x over previous
//
#include <hip/hip_runtime.h>
#include <hip/hip_bf16.h>

#define N_NODES 100000
#define M_PAD   100096            // 782 * 128, padded row count for MFMA GEMM
#define N_EDGES 1600000
#define E_TOT   (N_EDGES + N_NODES)   // + self loops
#define NEG_SLOPE 0.2f

typedef __attribute__((ext_vector_type(8))) short s16x8;
typedef __attribute__((ext_vector_type(4))) float f32x4;

__device__ __forceinline__ float lo16(unsigned u) { return __uint_as_float(u << 16); }
__device__ __forceinline__ float hi16(unsigned u) { return __uint_as_float(u & 0xffff0000u); }

// ---------------- CSR build ----------------

__global__ void degree_kernel(const int* __restrict__ dst, int* __restrict__ deg, int n) {
    int i = blockIdx.x * blockDim.x + threadIdx.x;
    if (i < n) atomicAdd(&deg[dst[i]], 1);
}

#define SCAN_BLOCK 256
#define SCAN_ITEMS 4
#define SCAN_NB ((N_NODES + SCAN_BLOCK * SCAN_ITEMS - 1) / (SCAN_BLOCK * SCAN_ITEMS))  // 98

__global__ void scan_partial(const int* __restrict__ deg, int* __restrict__ bsum, int n) {
    __shared__ int lds[SCAN_BLOCK];
    int base = blockIdx.x * SCAN_BLOCK * SCAN_ITEMS + threadIdx.x * SCAN_ITEMS;
    int s = 0;
    #pragma unroll
    for (int i = 0; i < SCAN_ITEMS; ++i) {
        int idx = base + i;
        if (idx < n) s += deg[idx] + 1;   // +1 = self loop
    }
    lds[threadIdx.x] = s;
    __syncthreads();
    for (int off = SCAN_BLOCK / 2; off; off >>= 1) {
        if (threadIdx.x < off) lds[threadIdx.x] += lds[threadIdx.x + off];
        __syncthreads();
    }
    if (threadIdx.x == 0) bsum[blockIdx.x] = lds[0];
}

__global__ void scan_bsum(int* bsum, int nb) {
    if (threadIdx.x == 0 && blockIdx.x == 0) {
        int acc = 0;
        for (int b = 0; b < nb; ++b) { int v = bsum[b]; bsum[b] = acc; acc += v; }
    }
}

__global__ void scan_final(const int* __restrict__ deg, const int* __restrict__ bsum,
                           int* __restrict__ rowptr, int* __restrict__ cursor, int n, int etot) {
    __shared__ int lds[SCAN_BLOCK];
    int tid = threadIdx.x;
    int base = blockIdx.x * SCAN_BLOCK * SCAN_ITEMS + tid * SCAN_ITEMS;
    int vals[SCAN_ITEMS];
    int s = 0;
    #pragma unroll
    for (int i = 0; i < SCAN_ITEMS; ++i) {
        int idx = base + i;
        vals[i] = (idx < n) ? deg[idx] + 1 : 0;
        s += vals[i];
    }
    lds[tid] = s;
    __syncthreads();
    for (int off = 1; off < SCAN_BLOCK; off <<= 1) {
        int v = 0;
        if (tid >= off) v = lds[tid - off];
        __syncthreads();
        if (tid >= off) lds[tid] += v;
        __syncthreads();
    }
    int excl = bsum[blockIdx.x] + lds[tid] - s;
    #pragma unroll
    for (int i = 0; i < SCAN_ITEMS; ++i) {
        int idx = base + i;
        if (idx < n) { rowptr[idx] = excl; cursor[idx] = excl; }
        excl += vals[i];
    }
    if (blockIdx.x == 0 && tid == 0) rowptr[n] = etot;
}

__global__ void scatter_kernel(const int* __restrict__ ei, int* __restrict__ cursor,
                               int* __restrict__ csr, int* __restrict__ csrd,
                               int E, int etot) {
    int e = blockIdx.x * blockDim.x + threadIdx.x;
    if (e >= etot) return;
    int s, d;
    if (e < E) { s = ei[e]; d = ei[E + e]; }
    else       { s = d = e - E; }
    int pos = atomicAdd(&cursor[d], 1);
    csr[pos] = s;
    csrd[pos] = d;
}

// ---------------- dtype conversion ----------------

__global__ void cvt_x_kernel(const float* __restrict__ in, __hip_bfloat16* __restrict__ out, int n4) {
    int i = blockIdx.x * blockDim.x + threadIdx.x;
    if (i >= n4) return;
    float4 v = ((const float4*)in)[i];
    __hip_bfloat162 a, b;
    a.x = __float2bfloat16(v.x); a.y = __float2bfloat16(v.y);
    b.x = __float2bfloat16(v.z); b.y = __float2bfloat16(v.w);
    *(__hip_bfloat162*)&out[(size_t)i * 4]     = a;
    *(__hip_bfloat162*)&out[(size_t)i * 4 + 2] = b;
}

// W [K][Nc] f32 -> Wt [Nc][K] bf16
__global__ void cvt_wt_kernel(const float* __restrict__ W, __hip_bfloat16* __restrict__ Wt, int K, int Nc) {
    int idx = blockIdx.x * blockDim.x + threadIdx.x;
    if (idx >= K * Nc) return;
    int k = idx / Nc, n = idx - k * Nc;
    Wt[n * K + k] = __float2bfloat16(W[idx]);
}

// ---------------- MFMA GEMM: C[m, :] = A[m, :] @ Bt^T, K = 128 ----------------
// block 256 = 4 waves (2 row-waves x 2 col-waves); each wave: 16 rows x NCOLS/2 cols.
// 4 row strips per block -> 128 rows/block. B kept entirely in registers.

template<int NCOLS>
__global__ __launch_bounds__(256) void mfma_gemm_kernel(const __hip_bfloat16* __restrict__ A,
                                                        const __hip_bfloat16* __restrict__ Bt,
                                                        __hip_bfloat16* __restrict__ C) {
    constexpr int CG = NCOLS / 32;           // 16-col groups per wave
    int wid = threadIdx.x >> 6;
    int lane = threadIdx.x & 63;
    int wr = wid >> 1, wc = wid & 1;
    int l15 = lane & 15, lk = lane >> 4;     // lk in 0..3

    s16x8 bfrag[CG][4];
    #pragma unroll
    for (int cg = 0; cg < CG; ++cg) {
        int col = wc * (NCOLS / 2) + cg * 16 + l15;
        #pragma unroll
        for (int ks = 0; ks < 4; ++ks)
            bfrag[cg][ks] = *(const s16x8*)&Bt[col * 128 + ks * 32 + lk * 8];
    }
    int rowblk = blockIdx.x * 128;
    #pragma unroll
    for (int st = 0; st < 4; ++st) {
        int rbase = rowblk + st * 32 + wr * 16;
        s16x8 afrag[4];
        #pragma unroll
        for (int ks = 0; ks < 4; ++ks)
            afrag[ks] = *(const s16x8*)&A[(size_t)(rbase + l15) * 128 + ks * 32 + lk * 8];
        f32x4 acc[CG];
        #pragma unroll
        for (int cg = 0; cg < CG; ++cg) acc[cg] = (f32x4){0.f, 0.f, 0.f, 0.f};
        #pragma unroll
        for (int ks = 0; ks < 4; ++ks) {
            #pragma unroll
            for (int cg = 0; cg < CG; ++cg)
                acc[cg] = __builtin_amdgcn_mfma_f32_16x16x32_bf16(afrag[ks], bfrag[cg][ks], acc[cg], 0, 0, 0);
        }
        #pragma unroll
        for (int cg = 0; cg < CG; ++cg) {
            int c = wc * (NCOLS / 2) + cg * 16 + l15;
            #pragma unroll
            for (int j = 0; j < 4; ++j)
                C[(size_t)(rbase + lk * 4 + j) * NCOLS + c] = __float2bfloat16(acc[cg][j]);
        }
    }
}

// ---------------- attention scores: s[n,h] = <h[n,h,:], att[h,:]> ----------------

template<int C, int J>
__global__ void score_kernel(const __hip_bfloat16* __restrict__ h, const float* __restrict__ att_src,
                             const float* __restrict__ att_dst,
                             float* __restrict__ s_src, float* __restrict__ s_dst, int n) {
    int idx = blockIdx.x * blockDim.x + threadIdx.x;   // node*4 + head
    if (idx >= n * 4) return;
    int node = idx >> 2, hd = idx & 3;
    const __hip_bfloat16* hp = h + (size_t)node * J + hd * C;
    const float* as = att_src + hd * C;
    const float* ad = att_dst + hd * C;
    float ss = 0.f, sd = 0.f;
    #pragma unroll
    for (int c8 = 0; c8 < C / 8; ++c8) {
        uint4 u = *(const uint4*)&hp[c8 * 8];   // 8 bf16
        const unsigned* uw = (const unsigned*)&u;
        #pragma unroll
        for (int t = 0; t < 4; ++t) {
            int c = c8 * 8 + t * 2;
            float v0 = lo16(uw[t]);
            float v1 = hi16(uw[t]);
            ss += v0 * as[c] + v1 * as[c + 1];
            sd += v0 * ad[c] + v1 * ad[c + 1];
        }
    }
    s_src[idx] = ss;
    s_dst[idx] = sd;
}

// ---------------- per-edge unnormalized softmax weights (CSR order) ----------------

__global__ void edge_p_kernel(const int* __restrict__ csr, const int* __restrict__ csrd,
                              const float* __restrict__ s_src, const float* __restrict__ s_dst,
                              float* __restrict__ p4, int etot) {
    int j = blockIdx.x * blockDim.x + threadIdx.x;
    if (j >= etot) return;
    int s = csr[j], d = csrd[j];
    float4 a = *(const float4*)&s_src[(size_t)s * 4];
    float4 b = *(const float4*)&s_dst[(size_t)d * 4];
    float4 r;
    float e;
    e = a.x + b.x; e = e > 0.f ? e : NEG_SLOPE * e; r.x = __expf(e);
    e = a.y + b.y; e = e > 0.f ? e : NEG_SLOPE * e; r.y = __expf(e);
    e = a.z + b.z; e = e > 0.f ? e : NEG_SLOPE * e; r.z = __expf(e);
    e = a.w + b.w; e = e > 0.f ? e : NEG_SLOPE * e; r.w = __expf(e);
    *(float4*)&p4[(size_t)j * 4] = r;
}

// ---------------- layer-1 aggregation (+bias +ELU), bf16 h ----------------
// one wave per dst (4 dst / block); lane owns 2 of 128 cols; edge loop unrolled x4.

__global__ __launch_bounds__(256) void agg1_kernel(
        const __hip_bfloat16* __restrict__ h1, const float* __restrict__ p4,
        const int* __restrict__ rowptr, const int* __restrict__ csr,
        const float* __restrict__ b1, __hip_bfloat16* __restrict__ out1) {
    int d = blockIdx.x * 4 + (threadIdx.x >> 6);
    if (d >= N_NODES) return;
    int lane = threadIdx.x & 63;
    int c0 = lane * 2;
    int hd = lane >> 4;
    float accx = 0.f, accy = 0.f, z = 0.f;
    int beg = rowptr[d], end = rowptr[d + 1];
    int j = beg;
    for (; j + 3 < end; j += 4) {
        int s0 = csr[j], s1 = csr[j + 1], s2 = csr[j + 2], s3 = csr[j + 3];
        float q0 = p4[(size_t)(j + 0) * 4 + hd];
        float q1 = p4[(size_t)(j + 1) * 4 + hd];
        float q2 = p4[(size_t)(j + 2) * 4 + hd];
        float q3 = p4[(size_t)(j + 3) * 4 + hd];
        unsigned u0 = *(const unsigned*)&h1[(size_t)s0 * 128 + c0];
        unsigned u1 = *(const unsigned*)&h1[(size_t)s1 * 128 + c0];
        unsigned u2 = *(const unsigned*)&h1[(size_t)s2 * 128 + c0];
        unsigned u3 = *(const unsigned*)&h1[(size_t)s3 * 128 + c0];
        accx += q0 * lo16(u0) + q1 * lo16(u1) + q2 * lo16(u2) + q3 * lo16(u3);
        accy += q0 * hi16(u0) + q1 * hi16(u1) + q2 * hi16(u2) + q3 * hi16(u3);
        z += q0 + q1 + q2 + q3;
    }
    for (; j < end; ++j) {
        int s = csr[j];
        float q = p4[(size_t)j * 4 + hd];
        unsigned u = *(const unsigned*)&h1[(size_t)s * 128 + c0];
        accx += q * lo16(u);
        accy += q * hi16(u);
        z += q;
    }
    float invz = 1.0f / z;
    float vx = accx * invz + b1[c0];
    float vy = accy * invz + b1[c0 + 1];
    vx = vx > 0.f ? vx : __expf(vx) - 1.0f;   // ELU
    vy = vy > 0.f ? vy : __expf(vy) - 1.0f;
    __hip_bfloat162 o;
    o.x = __float2bfloat16(vx);
    o.y = __float2bfloat16(vy);
    *(__hip_bfloat162*)&out1[(size_t)d * 128 + c0] = o;
}

// ---------------- layer-2 aggregation + head mean + b2 + log_softmax, bf16 h ----------------
// ONE wave per dst (4 dst / block). Lanes 0..39 each hold 4 cols (uint2 = 4 bf16);
// head = lane/10. Head-mean + log_softmax via shuffles, no LDS.

__global__ __launch_bounds__(256) void agg2_kernel(
        const __hip_bfloat16* __restrict__ h2, const float* __restrict__ p4,
        const int* __restrict__ rowptr, const int* __restrict__ csr,
        const float* __restrict__ b2, float* __restrict__ out) {
    int d = blockIdx.x * 4 + (threadIdx.x >> 6);
    if (d >= N_NODES) return;
    int lane = threadIdx.x & 63;
    bool active = lane < 40;
    int hd = lane / 10; if (hd > 3) hd = 3;
    float ax = 0.f, ay = 0.f, az = 0.f, aw = 0.f, z = 0.f;
    int beg = rowptr[d], end = rowptr[d + 1];
    int j = beg;
    for (; j + 3 < end; j += 4) {
        int s0 = csr[j], s1 = csr[j + 1], s2 = csr[j + 2], s3 = csr[j + 3];
        float q0 = p4[(size_t)(j + 0) * 4 + hd];
        float q1 = p4[(size_t)(j + 1) * 4 + hd];
        float q2 = p4[(size_t)(j + 2) * 4 + hd];
        float q3 = p4[(size_t)(j + 3) * 4 + hd];
        uint2 u0 = {0, 0}, u1 = {0, 0}, u2 = {0, 0}, u3 = {0, 0};
        if (active) {
            u0 = *(const uint2*)&h2[(size_t)s0 * 160 + lane * 4];
            u1 = *(const uint2*)&h2[(size_t)s1 * 160 + lane * 4];
            u2 = *(const uint2*)&h2[(size_t)s2 * 160 + lane * 4];
            u3 = *(const uint2*)&h2[(size_t)s3 * 160 + lane * 4];
        }
        ax += q0 * lo16(u0.x) + q1 * lo16(u1.x) + q2 * lo16(u2.x) + q3 * lo16(u3.x);
        ay += q0 * hi16(u0.x) + q1 * hi16(u1.x) + q2 * hi16(u2.x) + q3 * hi16(u3.x);
        az += q0 * lo16(u0.y) + q1 * lo16(u1.y) + q2 * lo16(u2.y) + q3 * lo16(u3.y);
        aw += q0 * hi16(u0.y) + q1 * hi16(u1.y) + q2 * hi16(u2.y) + q3 * hi16(u3.y);
        z += q0 + q1 + q2 + q3;
    }
    for (; j < end; ++j) {
        int s = csr[j];
        float q = p4[(size_t)j * 4 + hd];
        uint2 u = {0, 0};
        if (active) u = *(const uint2*)&h2[(size_t)s * 160 + lane * 4];
        ax += q * lo16(u.x);
        ay += q * hi16(u.x);
        az += q * lo16(u.y);
        aw += q * hi16(u.y);
        z += q;
    }
    float invz = 1.0f / z;
    float rx = ax * invz, ry = ay * invz, rz = az * invz, rw = aw * invz;
    // head mean: lanes 0..9 sum lanes l, l+10, l+20, l+30
    float sx = rx + __shfl(rx, lane + 10) + __shfl(rx, lane + 20) + __shfl(rx, lane + 30);
    float sy = ry + __shfl(ry, lane + 10) + __shfl(ry, lane + 20) + __shfl(ry, lane + 30);
    float sz = rz + __shfl(rz, lane + 10) + __shfl(rz, lane + 20) + __shfl(rz, lane + 30);
    float sw = rw + __shfl(rw, lane + 10) + __shfl(rw, lane + 20) + __shfl(rw, lane + 30);
    int lc = lane < 10 ? lane : 9;
    float4 bb = *(const float4*)&b2[lc * 4];
    bool own = lane < 10;
    float vx = own ? sx * 0.25f + bb.x : -1e30f;
    float vy = own ? sy * 0.25f + bb.y : -1e30f;
    float vz = own ? sz * 0.25f + bb.z : -1e30f;
    float vw = own ? sw * 0.25f + bb.w : -1e30f;
    float m = fmaxf(fmaxf(vx, vy), fmaxf(vz, vw));
    #pragma unroll
    for (int off = 1; off < 16; off <<= 1) m = fmaxf(m, __shfl_xor(m, off));
    float ssum = 0.f;
    float ex = 0.f, ey = 0.f, ez = 0.f, ew = 0.f;
    if (own) {
        ex = __expf(vx - m); ey = __expf(vy - m);
        ez = __expf(vz - m); ew = __expf(vw - m);
        ssum = ex + ey + ez + ew;
    }
    #pragma unroll
    for (int off = 1; off < 16; off <<= 1) ssum += __shfl_xor(ssum, off);
    float lse = m + __logf(ssum);
    if (own) {
        float4 o = {vx - lse, vy - lse, vz - lse, vw - lse};
        *(float4*)&out[(size_t)d * 40 + lane * 4] = o;
    }
}

// ---------------- launch ----------------

extern "C" void kernel_launch(void* const* d_in, const int* in_sizes, int n_in,
                              void* d_out, int out_size, void* d_ws, size_t ws_size,
                              hipStream_t stream) {
    const float* x   = (const float*)d_in[0];
    const int*   ei  = (const int*)d_in[1];
    const float* W1  = (const float*)d_in[2];
    const float* as1 = (const float*)d_in[3];
    const float* ad1 = (const float*)d_in[4];
    const float* b1  = (const float*)d_in[5];
    const float* W2  = (const float*)d_in[6];
    const float* as2 = (const float*)d_in[7];
    const float* ad2 = (const float*)d_in[8];
    const float* b2  = (const float*)d_in[9];
    float* out = (float*)d_out;

    char* ws = (char*)d_ws;
    size_t off = 0;
    auto alloc = [&](size_t bytes) {
        void* p = ws + off;
        off += (bytes + 255) & ~(size_t)255;
        return p;
    };
    __hip_bfloat16* xb    = (__hip_bfloat16*)alloc((size_t)M_PAD * 128 * 2);
    __hip_bfloat16* h1b   = (__hip_bfloat16*)alloc((size_t)M_PAD * 128 * 2);
    __hip_bfloat16* out1b = (__hip_bfloat16*)alloc((size_t)M_PAD * 128 * 2);
    __hip_bfloat16* h2b   = (__hip_bfloat16*)alloc((size_t)M_PAD * 160 * 2);
    __hip_bfloat16* W1t   = (__hip_bfloat16*)alloc((size_t)128 * 128 * 2);
    __hip_bfloat16* W2t   = (__hip_bfloat16*)alloc((size_t)160 * 128 * 2);
    float* s_src1  = (float*)alloc((size_t)N_NODES * 4 * 4);
    float* s_dst1  = (float*)alloc((size_t)N_NODES * 4 * 4);
    float* s_src2  = (float*)alloc((size_t)N_NODES * 4 * 4);
    float* s_dst2  = (float*)alloc((size_t)N_NODES * 4 * 4);
    float* p4      = (float*)alloc((size_t)E_TOT * 4 * 4);
    int*   deg     = (int*)alloc((size_t)N_NODES * 4);
    int*   rowptr  = (int*)alloc((size_t)(N_NODES + 1) * 4);
    int*   cursor  = (int*)alloc((size_t)N_NODES * 4);
    int*   csr     = (int*)alloc((size_t)E_TOT * 4);
    int*   csrd    = (int*)alloc((size_t)E_TOT * 4);
    int*   bsum    = (int*)alloc((size_t)SCAN_NB * 4);

    // CSR build
    hipMemsetAsync(deg, 0, (size_t)N_NODES * 4, stream);
    degree_kernel<<<(N_EDGES + 255) / 256, 256, 0, stream>>>(ei + N_EDGES, deg, N_EDGES);
    scan_partial<<<SCAN_NB, SCAN_BLOCK, 0, stream>>>(deg, bsum, N_NODES);
    scan_bsum<<<1, 64, 0, stream>>>(bsum, SCAN_NB);
    scan_final<<<SCAN_NB, SCAN_BLOCK, 0, stream>>>(deg, bsum, rowptr, cursor, N_NODES, E_TOT);
    scatter_kernel<<<(E_TOT + 255) / 256, 256, 0, stream>>>(ei, cursor, csr, csrd, N_EDGES, E_TOT);

    // dtype prep
    cvt_x_kernel<<<(N_NODES * 32 + 255) / 256, 256, 0, stream>>>(x, xb, N_NODES * 32);
    cvt_wt_kernel<<<(128 * 128 + 255) / 256, 256, 0, stream>>>(W1, W1t, 128, 128);
    cvt_wt_kernel<<<(128 * 160 + 255) / 256, 256, 0, stream>>>(W2, W2t, 128, 160);

    // layer 1
    mfma_gemm_kernel<128><<<M_PAD / 128, 256, 0, stream>>>(xb, W1t, h1b);
    score_kernel<32, 128><<<(N_NODES * 4 + 255) / 256, 256, 0, stream>>>(h1b, as1, ad1, s_src1, s_dst1, N_NODES);
    edge_p_kernel<<<(E_TOT + 255) / 256, 256, 0, stream>>>(csr, csrd, s_src1, s_dst1, p4, E_TOT);
    agg1_kernel<<<(N_NODES + 3) / 4, 256, 0, stream>>>(h1b, p4, rowptr, csr, b1, out1b);

    // layer 2
    mfma_gemm_kernel<160><<<M_PAD / 128, 256, 0, stream>>>(out1b, W2t, h2b);
    score_kernel<40, 160><<<(N_NODES * 4 + 255) / 256, 256, 0, stream>>>(h2b, as2, ad2, s_src2, s_dst2, N_NODES);
    edge_p_kernel<<<(E_TOT + 255) / 256, 256, 0, stream>>>(csr, csrd, s_src2, s_dst2, p4, E_TOT);
    agg2_kernel<<<(N_NODES + 3) / 4, 256, 0, stream>>>(h2b, p4, rowptr, csr, b2, out);
}